// Round 7
// baseline (27.246 us; speedup 1.0000x reference)
//
#include <hip/hip_runtime.h>

// Problem constants (match reference)
constexpr int V     = 50265;   // vocab size
constexpr int PADT  = 1;       // PAD token id
constexpr int BATCH = 512;
constexpr int SEQ   = 512;
constexpr int SS    = 6284;    // vocab section (mult of 4; 8*6284 >= V)
constexpr int HW4   = 3144;    // 3142 packed u16-pair words, padded to uint4
constexpr int NPART = 64;      // one wave's worth of partials

// Kernel 1: 64 block-partials of the global non-PAD token count.
// Every slot written every call (no zero-init dependency, deterministic).
__global__ __launch_bounds__(512) void k_partial(const int4* __restrict__ ids4,
                                                 int* __restrict__ partials) {
    const int t = threadIdx.x, b = blockIdx.x;
    const int4 a = ids4[b * 1024 + t];          // 64 blk * 512 thr * 8 tok = 262144
    const int4 c4 = ids4[b * 1024 + 512 + t];
    int c = (a.x != PADT) + (a.y != PADT) + (a.z != PADT) + (a.w != PADT)
          + (c4.x != PADT) + (c4.y != PADT) + (c4.z != PADT) + (c4.w != PADT);
    #pragma unroll
    for (int off = 32; off > 0; off >>= 1) c += __shfl_down(c, off, 64);
    __shared__ int sc[8];
    if ((t & 63) == 0) sc[t >> 6] = c;
    __syncthreads();
    if (t == 0) {
        int s = 0;
        #pragma unroll
        for (int j = 0; j < 8; ++j) s += sc[j];
        partials[b] = s;
    }
}

// Kernel 2: 2048 blocks x 256 threads (8 blocks/CU, one resident round).
// Each block = (row, quarter): preamble once, two vocab sections through a
// 12.6 KB u16-packed LDS histogram. NEW vs R6: 16B/lane stores
// (global_store_dwordx4, 1KB/wave-instr) with per-row alignment phase
// a = (-b)&3 (V % 4 == 1 makes odd rows 16B-misaligned); <=3 head/tail
// elements per section handled scalar. Hist read as u16 loads (parity-free).
__global__ __launch_bounds__(256) void k_fused(const int* __restrict__ ids,
                                               const int* __restrict__ partials,
                                               float* __restrict__ out) {
    __shared__ unsigned hist[HW4];
    __shared__ int s_red[4];
    __shared__ float s_add;

    const int bs = blockIdx.x;
    const int b = bs >> 2, h = bs & 3;   // row, quarter
    const int t = threadIdx.x;

    // issue global loads immediately; latency hides under the reduces
    int pv = (t < NPART) ? partials[t] : 0;
    const int id0 = ids[b * SEQ + t];
    const int id1 = ids[b * SEQ + 256 + t];

    // row non-PAD length (block reduce over 4 waves)
    int np = ((id0 != PADT) ? 1 : 0) + ((id1 != PADT) ? 1 : 0);
    #pragma unroll
    for (int off = 32; off > 0; off >>= 1) np += __shfl_down(np, off, 64);
    if ((t & 63) == 0) s_red[t >> 6] = np;
    __syncthreads();

    if (t < NPART) {
        // wave-parallel global total (loads issued at kernel entry)
        #pragma unroll
        for (int off = 32; off > 0; off >>= 1) pv += __shfl_down(pv, off, 64);
        if (t == 0) {
            int dl = s_red[0] + s_red[1] + s_red[2] + s_red[3];
            // d_avg = dl / (total/BATCH); dl*BATCH <= 2^18, exact in fp32
            float d_avg = (float)dl * (float)BATCH / (float)pv;
            s_add = 1.6f * (0.25f + 0.75f * d_avg);  // k*(1-b+b*d_avg)
        }
    }
    __syncthreads();

    const float addend = s_add;
    const unsigned short* h16 = (const unsigned short*)hist;
    float* __restrict__ orow = out + (size_t)b * V;
    const int a = (-b) & 3;   // (b*V + v) % 4 == 0  iff  v % 4 == a  (V%4==1)

    #pragma unroll 1
    for (int ph = 0; ph < 2; ++ph) {
        const int q = h * 2 + ph;
        const int v0 = q * SS;
        const int vend = (v0 + SS < V) ? (v0 + SS) : V;

        // zero histogram with 16B LDS writes (786 uint4 / 256 thr ~ 3 iters)
        uint4* h4 = (uint4*)hist;
        const uint4 z4 = make_uint4(0u, 0u, 0u, 0u);
        #pragma unroll
        for (int w = t; w < HW4 / 4; w += 256) h4[w] = z4;
        __syncthreads();

        // scatter my 2 tokens if in this section (u16-packed; counts <= 512)
        if (id0 != PADT && id0 >= v0 && id0 < vend) {
            const int li = id0 - v0;
            atomicAdd(&hist[li >> 1], 1u << ((li & 1) * 16));
        }
        if (id1 != PADT && id1 >= v0 && id1 < vend) {
            const int li = id1 - v0;
            atomicAdd(&hist[li >> 1], 1u << ((li & 1) * 16));
        }
        __syncthreads();

        // head: a (<=3) scalar elements before the first aligned group
        if (t < a) {
            const int v = v0 + t;
            const float fc = (float)h16[v - v0];
            orow[v] = (fc * 2.6f) * __builtin_amdgcn_rcpf(fc + addend);
        }

        // main: 16B-aligned float4 groups (1KB/wave contiguous stores)
        const int vA = v0 + a;
        const int ngroups = (vend - vA) >> 2;
        for (int g = t; g < ngroups; g += 256) {
            const int li = a + g * 4;
            const float fc0 = (float)h16[li + 0];
            const float fc1 = (float)h16[li + 1];
            const float fc2 = (float)h16[li + 2];
            const float fc3 = (float)h16[li + 3];
            float4 r;
            r.x = (fc0 * 2.6f) * __builtin_amdgcn_rcpf(fc0 + addend);
            r.y = (fc1 * 2.6f) * __builtin_amdgcn_rcpf(fc1 + addend);
            r.z = (fc2 * 2.6f) * __builtin_amdgcn_rcpf(fc2 + addend);
            r.w = (fc3 * 2.6f) * __builtin_amdgcn_rcpf(fc3 + addend);
            *reinterpret_cast<float4*>(orow + vA + g * 4) = r;
        }

        // tail: remaining (vend - vA) & 3 scalar elements
        const int tv = vA + (ngroups << 2);
        if (t < vend - tv) {
            const int v = tv + t;
            const float fc = (float)h16[v - v0];
            orow[v] = (fc * 2.6f) * __builtin_amdgcn_rcpf(fc + addend);
        }
        __syncthreads();   // protect hist re-zero of the next section
    }
}

extern "C" void kernel_launch(void* const* d_in, const int* in_sizes, int n_in,
                              void* d_out, int out_size, void* d_ws, size_t ws_size,
                              hipStream_t stream) {
    const int* ids = (const int*)d_in[0];   // input_ids, int32 [512*512]
    // d_in[1] = beta (unused by the reference computation)
    float* out = (float*)d_out;             // [512 * 50265] fp32
    int* partials = (int*)d_ws;             // NPART ints of scratch

    k_partial<<<NPART, 512, 0, stream>>>((const int4*)ids, partials);
    k_fused<<<BATCH * 4, 256, 0, stream>>>(ids, partials, out);
}